// Round 1
// baseline (147.057 us; speedup 1.0000x reference)
//
#include <hip/hip_runtime.h>
#include <math.h>

#define HDIM 128
#define WDIM 128
#define CDIM 64
#define BDIM 4
#define NPIX (BDIM * HDIM * WDIM)   // 65536

// ---------------------------------------------------------------------------
// Kernel 1: dual 1x1 conv (per-pixel channel matmul), fp32 vector ALU.
//   GEMM: [NPIX x 64] @ [64 x 64] for (x_main,W_main)->cm and (x_ref,W_ref)->cr
//   blockIdx.y in {0,1} selects which.
//   Block tile: 128 px x 64 d, 256 threads, micro-tile 4 px x 8 d per thread.
//   LDS: W[c][d] 16 KB + x transposed [c][px] (stride 132, bank-shift 4) 33 KB.
// ---------------------------------------------------------------------------
__global__ void conv1x1_kernel(const float* __restrict__ xm,
                               const float* __restrict__ xr,
                               const float* __restrict__ Wm,
                               const float* __restrict__ Wr,
                               float* __restrict__ outm,
                               float* __restrict__ outr) {
    const float* x; const float* Wg; float* out;
    if (blockIdx.y == 0) { x = xm; Wg = Wm; out = outm; }
    else                 { x = xr; Wg = Wr; out = outr; }

    __shared__ float Ws[CDIM][CDIM];   // [c][d]
    __shared__ float xs[CDIM][132];    // [c][px] padded: 132 mod 32 = 4 bank shift

    const int t = threadIdx.x;
    const int pxbase = blockIdx.x * 128;

    // stage W: 4096 floats = 1024 float4
    {
        const float4* Wg4 = (const float4*)Wg;
        float4* Ws4 = (float4*)&Ws[0][0];
        #pragma unroll
        for (int i = 0; i < 4; ++i) Ws4[t + 256 * i] = Wg4[t + 256 * i];
    }
    // stage x tile transposed: 128 px x 64 c = 2048 float4 loads
    #pragma unroll
    for (int i = 0; i < 8; ++i) {
        int L  = t + 256 * i;
        int px = L >> 4;          // [0,128)
        int c4 = L & 15;          // float4 chunk within channel dim
        float4 v = *(const float4*)&x[(size_t)(pxbase + px) * CDIM + 4 * c4];
        xs[4 * c4 + 0][px] = v.x;
        xs[4 * c4 + 1][px] = v.y;
        xs[4 * c4 + 2][px] = v.z;
        xs[4 * c4 + 3][px] = v.w;
    }
    __syncthreads();

    const int dg = t & 7;    // 8 d-groups of 8 cols
    const int pg = t >> 3;   // 32 px-groups of 4 rows

    float acc[4][8];
    #pragma unroll
    for (int i = 0; i < 4; ++i)
        #pragma unroll
        for (int j = 0; j < 8; ++j) acc[i][j] = 0.f;

    #pragma unroll 16
    for (int c = 0; c < CDIM; ++c) {
        float4 xv = *(const float4*)&xs[c][pg * 4];
        float4 w0 = *(const float4*)&Ws[c][dg * 8];
        float4 w1 = *(const float4*)&Ws[c][dg * 8 + 4];
        float xa[4] = {xv.x, xv.y, xv.z, xv.w};
        float wa[8] = {w0.x, w0.y, w0.z, w0.w, w1.x, w1.y, w1.z, w1.w};
        #pragma unroll
        for (int i = 0; i < 4; ++i)
            #pragma unroll
            for (int j = 0; j < 8; ++j)
                acc[i][j] = fmaf(xa[i], wa[j], acc[i][j]);
    }

    #pragma unroll
    for (int i = 0; i < 4; ++i) {
        int px = pxbase + pg * 4 + i;
        float4 o0 = {acc[i][0], acc[i][1], acc[i][2], acc[i][3]};
        float4 o1 = {acc[i][4], acc[i][5], acc[i][6], acc[i][7]};
        *(float4*)&out[(size_t)px * CDIM + dg * 8]     = o0;
        *(float4*)&out[(size_t)px * CDIM + dg * 8 + 4] = o1;
    }
}

// ---------------------------------------------------------------------------
// Kernel 2: 25 shifted dot-products + self score + softmax(26).
//   2 threads per pixel (channel halves 0..31 / 32..63), pair shfl-reduce.
//   OOB neighbors contribute score EXACTLY 0 (reference zero-pads keys).
// ---------------------------------------------------------------------------
__global__ void attn_kernel(const float* __restrict__ cm,
                            const float* __restrict__ cr,
                            float* __restrict__ out) {
    const int gid  = blockIdx.x * blockDim.x + threadIdx.x;
    const int px   = gid >> 1;
    const int cg   = gid & 1;
    const int coff = cg * 32;

    const int w = px & (WDIM - 1);
    const int h = (px >> 7) & (HDIM - 1);

    float4 cmv[8];
    {
        const float4* cmp = (const float4*)&cm[(size_t)px * CDIM + coff];
        #pragma unroll
        for (int m = 0; m < 8; ++m) cmv[m] = cmp[m];
    }

    float s[26];
    #pragma unroll
    for (int k = 0; k < 25; ++k) {
        const int i  = k / 5, j = k % 5;
        const int hh = h + i - 2, ww = w + j - 2;
        float acc = 0.f;
        if (hh >= 0 && hh < HDIM && ww >= 0 && ww < WDIM) {
            const int npx = px + (i - 2) * WDIM + (j - 2);
            const float4* crp = (const float4*)&cr[(size_t)npx * CDIM + coff];
            #pragma unroll
            for (int m = 0; m < 8; ++m) {
                float4 v = crp[m];
                acc = fmaf(cmv[m].x, v.x, acc);
                acc = fmaf(cmv[m].y, v.y, acc);
                acc = fmaf(cmv[m].z, v.z, acc);
                acc = fmaf(cmv[m].w, v.w, acc);
            }
        }
        s[k] = acc;
    }
    {
        float acc = 0.f;
        #pragma unroll
        for (int m = 0; m < 8; ++m) {
            float4 v = cmv[m];
            acc = fmaf(v.x, v.x, acc);
            acc = fmaf(v.y, v.y, acc);
            acc = fmaf(v.z, v.z, acc);
            acc = fmaf(v.w, v.w, acc);
        }
        s[25] = acc;
    }

    // combine the two channel halves (lanes 2k / 2k+1 hold same pixel)
    #pragma unroll
    for (int k = 0; k < 26; ++k) s[k] += __shfl_xor(s[k], 1);

    // softmax over 26 (both lanes redundantly compute full result)
    float mx = s[0];
    #pragma unroll
    for (int k = 1; k < 26; ++k) mx = fmaxf(mx, s[k]);
    float sum = 0.f;
    #pragma unroll
    for (int k = 0; k < 26; ++k) { s[k] = __expf(s[k] - mx); sum += s[k]; }
    const float inv = 1.f / sum;

    // each lane of the pair writes 13 of the 26 outputs
    float* op = &out[(size_t)px * 26];
    const int kb = cg * 13;
    #pragma unroll
    for (int k = 0; k < 13; ++k) op[kb + k] = s[kb + k] * inv;
}

// ---------------------------------------------------------------------------
extern "C" void kernel_launch(void* const* d_in, const int* in_sizes, int n_in,
                              void* d_out, int out_size, void* d_ws, size_t ws_size,
                              hipStream_t stream) {
    const float* xm = (const float*)d_in[0];
    const float* xr = (const float*)d_in[1];
    const float* Wm = (const float*)d_in[2];
    const float* Wr = (const float*)d_in[3];
    float* outp = (float*)d_out;

    float* cm = (float*)d_ws;                       // NPIX*64 floats
    float* cr = cm + (size_t)NPIX * CDIM;           // NPIX*64 floats (33.6 MB total)

    dim3 g1(NPIX / 128, 2);
    conv1x1_kernel<<<g1, 256, 0, stream>>>(xm, xr, Wm, Wr, cm, cr);

    attn_kernel<<<(NPIX * 2) / 256, 256, 0, stream>>>(cm, cr, outp);
}